// Round 6
// baseline (276.347 us; speedup 1.0000x reference)
//
#include <hip/hip_runtime.h>
#include <hip/hip_cooperative_groups.h>
#include <stdint.h>

namespace cg = cooperative_groups;

#define N_TOTAL 4096
#define DIMS 256
#define M_HALF 2048
#define NNEIGH 30
#define NTILES 1024   // (4096/128)^2
#define GRID 256      // 256 blocks x 512 thr; coop limit = 2 blk/CU * 256 = 512 (2x margin)

typedef __bf16 bf16_t;
typedef bf16_t bf16x8 __attribute__((ext_vector_type(8)));
typedef float f32x4 __attribute__((ext_vector_type(4)));
typedef unsigned short ushort8 __attribute__((ext_vector_type(8)));

typedef __attribute__((address_space(3))) uint32_t lds_u32;
typedef const __attribute__((address_space(1))) uint32_t glb_u32;

__device__ inline uint16_t f2bf(float f) {
    union { float f; uint32_t u; } v; v.f = f;
    uint32_t u = v.u;
    uint32_t r = (u + 0x7fffu + ((u >> 16) & 1u)) >> 16;  // RNE
    return (uint16_t)r;
}

// ---------------- fused cooperative kernel (512 threads) ----------------

// Stage a 128x64 bf16 panel pair into LDS buffer `buf` (512-thread version).
// LDS dest linear (global_load_lds rule); XOR swizzle via global source chunk.
__device__ inline void stage512(const uint16_t* __restrict__ F, char* smem,
                                int buf, int k0, int rowA0, int rowB0, int tid) {
    const int wid = tid >> 6;
    #pragma unroll
    for (int i = 0; i < 2; ++i) {
        int p = i * 512 + tid;          // 16B-chunk index within 16KB panel
        int row = p >> 3;
        int pc = p & 7;
        int c = pc ^ (row & 7);
        const uint16_t* ga = F + (size_t)(rowA0 + row) * DIMS + k0 + c * 8;
        char* la = smem + buf * 32768 + i * 8192 + wid * 1024;
        __builtin_amdgcn_global_load_lds((glb_u32*)ga, (lds_u32*)la, 16, 0, 0);
    }
    #pragma unroll
    for (int i = 0; i < 2; ++i) {
        int p = i * 512 + tid;
        int row = p >> 3;
        int pc = p & 7;
        int c = pc ^ (row & 7);
        const uint16_t* gb = F + (size_t)(rowB0 + row) * DIMS + k0 + c * 8;
        char* lb = smem + buf * 32768 + 16384 + i * 8192 + wid * 1024;
        __builtin_amdgcn_global_load_lds((glb_u32*)gb, (lds_u32*)lb, 16, 0, 0);
    }
}

__global__ __launch_bounds__(512, 2) void fused_kernel(const float* __restrict__ emb,
                                                       uint16_t* __restrict__ F,
                                                       float* __restrict__ den,
                                                       float* __restrict__ num,
                                                       float* __restrict__ out) {
    __shared__ char smem[65536];
    const int tid = threadIdx.x;
    const int b = blockIdx.x;
    cg::grid_group grid = cg::this_grid();

    // ---- Phase 1: normalize + transpose, 16 seq positions per block ----
    {
        float* tf = (float*)smem;            // [16][257]
        float* invn = tf + 16 * 257;
        const int bi = b >> 4;
        const int l0 = (b & 15) * 16;
        const float* src = emb + (size_t)bi * DIMS * 256 + l0;
        #pragma unroll
        for (int it = 0; it < 8; ++it) {
            int idx = it * 512 + tid;
            int l = idx & 15;
            int d = idx >> 4;
            tf[l * 257 + d] = src[(size_t)d * 256 + l];
        }
        if (tid < 16) den[b * 16 + tid] = 0.f;
        if (b == 0 && tid == 0) out[0] = 0.f;
        __syncthreads();
        {
            int l = tid >> 5;    // 16 rows x 32 threads
            int c = tid & 31;
            float ss = 0.f;
            #pragma unroll
            for (int k = 0; k < 8; ++k) {
                float v = tf[l * 257 + c + 32 * k];
                ss += v * v;
            }
            ss += __shfl_xor(ss, 1, 64);
            ss += __shfl_xor(ss, 2, 64);
            ss += __shfl_xor(ss, 4, 64);
            ss += __shfl_xor(ss, 8, 64);
            ss += __shfl_xor(ss, 16, 64);
            if (c == 0) invn[l] = 1.0f / fmaxf(sqrtf(ss), 1e-12f);
        }
        __syncthreads();
        {
            int l = tid & 15;
            int q = tid >> 4;    // 32 chunks of 8 d
            float s = invn[l];
            ushort8 v;
            #pragma unroll
            for (int j = 0; j < 8; ++j) v[j] = f2bf(tf[l * 257 + q * 8 + j] * s);
            int r = bi * 256 + l0 + l;
            *(ushort8*)(F + (size_t)r * DIMS + q * 8) = v;
        }
    }
    // release dirty L2 (F, den=0, out=0) -> coherence point; acquire after barrier
    __threadfence();
    grid.sync();
    __threadfence();

    // ---- Phase 2: sims = F*F^T (128x128 tiles, 8 waves: 2 row x 4 col) ----
    const int wid = tid >> 6;
    const int lane = tid & 63;
    const int lr = lane & 15;
    const int kg = lane >> 4;
    const int wr = wid >> 2, wc = wid & 3;
    const float invT = 1.0f / 0.07f;
    const float slope = 1.0f / (float)NNEIGH;

    for (int tile = b; tile < NTILES; tile += GRID) {
        const int swz = (tile & 7) * 128 + (tile >> 3);  // XCD-aware, bijective
        const int bm = swz >> 5, bn = swz & 31;
        const int rowA0 = bm * 128, rowB0 = bn * 128;

        f32x4 acc[4][2];
        #pragma unroll
        for (int a = 0; a < 4; ++a)
            #pragma unroll
            for (int bb = 0; bb < 2; ++bb) acc[a][bb] = (f32x4){0.f, 0.f, 0.f, 0.f};

        stage512(F, smem, 0, 0, rowA0, rowB0, tid);
        __syncthreads();

        for (int tt = 0; tt < 4; ++tt) {
            const int cur = tt & 1;
            if (tt < 3) stage512(F, smem, cur ^ 1, (tt + 1) * 64, rowA0, rowB0, tid);
            const char* Ab = smem + cur * 32768;
            const char* Bb = Ab + 16384;
            #pragma unroll
            for (int kk = 0; kk < 2; ++kk) {
                bf16x8 af[4], bfr[2];
                #pragma unroll
                for (int a = 0; a < 4; ++a) {
                    int r = wr * 64 + a * 16 + lr;
                    int pc = (kk * 4 + kg) ^ (r & 7);
                    af[a] = *(const bf16x8*)(Ab + r * 128 + pc * 16);
                }
                #pragma unroll
                for (int bb = 0; bb < 2; ++bb) {
                    int r = wc * 32 + bb * 16 + lr;
                    int pc = (kk * 4 + kg) ^ (r & 7);
                    bfr[bb] = *(const bf16x8*)(Bb + r * 128 + pc * 16);
                }
                #pragma unroll
                for (int a = 0; a < 4; ++a)
                    #pragma unroll
                    for (int bb = 0; bb < 2; ++bb)
                        acc[a][bb] = __builtin_amdgcn_mfma_f32_16x16x32_bf16(af[a], bfr[bb], acc[a][bb], 0, 0, 0);
            }
            __syncthreads();
        }

        const int i0 = rowA0 + wr * 64;
        const int j0 = rowB0 + wc * 32;
        float rs[4][4];
        #pragma unroll
        for (int a = 0; a < 4; ++a)
            #pragma unroll
            for (int e = 0; e < 4; ++e) rs[a][e] = 0.f;

        #pragma unroll
        for (int a = 0; a < 4; ++a) {
            #pragma unroll
            for (int bb = 0; bb < 2; ++bb) {
                const int col = j0 + bb * 16 + lr;
                #pragma unroll
                for (int e = 0; e < 4; ++e) {
                    const int row = i0 + a * 16 + kg * 4 + e;
                    const int d = col - row;
                    float wv = (d >= 0) ? fminf((float)d * slope, 1.0f)
                                        : ((d >= -NNEIGH) ? (float)(-d - 1) * slope : 1.0f);
                    float v = __expf(acc[a][bb][e] * invT) * wv;
                    rs[a][e] += v;
                    int pcl = row + M_HALF;
                    if (pcl >= N_TOTAL) pcl -= N_TOTAL;
                    if (col == pcl) num[row] = v;   // one writer; fence publishes
                }
            }
        }
        #pragma unroll
        for (int a = 0; a < 4; ++a)
            #pragma unroll
            for (int e = 0; e < 4; ++e) {
                float s = rs[a][e];
                s += __shfl_xor(s, 1, 64);
                s += __shfl_xor(s, 2, 64);
                s += __shfl_xor(s, 4, 64);
                s += __shfl_xor(s, 8, 64);
                if (lr == 0) atomicAdd(&den[i0 + a * 16 + kg * 4 + e], s);
            }
        __syncthreads();
    }
    __threadfence();
    grid.sync();
    __threadfence();

    // ---- Phase 3: mean of num/den (8 blocks x 512 rows) ----
    if (b < 8) {
        float* sb = (float*)smem;
        int r = b * 512 + tid;
        float s = num[r] / den[r];
        s += __shfl_xor(s, 1, 64);
        s += __shfl_xor(s, 2, 64);
        s += __shfl_xor(s, 4, 64);
        s += __shfl_xor(s, 8, 64);
        s += __shfl_xor(s, 16, 64);
        s += __shfl_xor(s, 32, 64);
        if ((tid & 63) == 0) sb[tid >> 6] = s;
        __syncthreads();
        if (tid == 0) {
            float t = 0.f;
            #pragma unroll
            for (int w = 0; w < 8; ++w) t += sb[w];
            atomicAdd(out, t * (1.0f / (float)N_TOTAL));
        }
    }
}

// ---------------- fallback: verified R2 three-kernel path ----------------

__global__ __launch_bounds__(256) void nt_kernel(const float* __restrict__ emb,
                                                 uint16_t* __restrict__ F,
                                                 float* __restrict__ den) {
    __shared__ float tile[16][257];
    __shared__ float invn[16];
    const int bi = blockIdx.x >> 4;
    const int lc = blockIdx.x & 15;
    const int l0 = lc * 16;
    const int tid = threadIdx.x;
    if (tid < 16) den[blockIdx.x * 16 + tid] = 0.f;
    const float* src = emb + (size_t)bi * DIMS * 256 + l0;
    #pragma unroll
    for (int p = 0; p < 16; ++p) {
        int idx = p * 256 + tid;
        int l = idx & 15;
        int d = idx >> 4;
        tile[l][d] = src[(size_t)d * 256 + l];
    }
    __syncthreads();
    {
        int l = tid >> 4;
        int c = tid & 15;
        float ss = 0.f;
        #pragma unroll
        for (int d = 0; d < 256; d += 16) {
            float v = tile[l][d + c];
            ss += v * v;
        }
        ss += __shfl_xor(ss, 1, 64);
        ss += __shfl_xor(ss, 2, 64);
        ss += __shfl_xor(ss, 4, 64);
        ss += __shfl_xor(ss, 8, 64);
        if (c == 0) invn[l] = 1.0f / fmaxf(sqrtf(ss), 1e-12f);
    }
    __syncthreads();
    #pragma unroll
    for (int p = 0; p < 16; ++p) {
        int r = bi * 256 + l0 + p;
        F[(size_t)r * DIMS + tid] = f2bf(tile[p][tid] * invn[p]);
    }
}

__device__ inline void stage256(const uint16_t* __restrict__ F, char* smem,
                                int buf, int k0, int rowA0, int rowB0, int tid) {
    const int wid = tid >> 6;
    #pragma unroll
    for (int i = 0; i < 4; ++i) {
        int p = i * 256 + tid;
        int row = p >> 3;
        int pc = p & 7;
        int c = pc ^ (row & 7);
        const uint16_t* ga = F + (size_t)(rowA0 + row) * DIMS + k0 + c * 8;
        char* la = smem + buf * 32768 + i * 4096 + wid * 1024;
        __builtin_amdgcn_global_load_lds((glb_u32*)ga, (lds_u32*)la, 16, 0, 0);
    }
    #pragma unroll
    for (int i = 0; i < 4; ++i) {
        int p = i * 256 + tid;
        int row = p >> 3;
        int pc = p & 7;
        int c = pc ^ (row & 7);
        const uint16_t* gb = F + (size_t)(rowB0 + row) * DIMS + k0 + c * 8;
        char* lb = smem + buf * 32768 + 16384 + i * 4096 + wid * 1024;
        __builtin_amdgcn_global_load_lds((glb_u32*)gb, (lds_u32*)lb, 16, 0, 0);
    }
}

__global__ __launch_bounds__(256) void sim_kernel(const uint16_t* __restrict__ F,
                                                  float* __restrict__ den,
                                                  float* __restrict__ num) {
    __shared__ char smem[65536];
    const int tid = threadIdx.x;
    const int wid = tid >> 6;
    const int lane = tid & 63;
    const int lr = lane & 15;
    const int kg = lane >> 4;
    const int wr = wid >> 1, wc = wid & 1;

    const int bid = blockIdx.x;
    const int swz = (bid & 7) * 128 + (bid >> 3);
    const int bm = swz >> 5, bn = swz & 31;
    const int rowA0 = bm * 128, rowB0 = bn * 128;

    f32x4 acc[4][4];
    #pragma unroll
    for (int a = 0; a < 4; ++a)
        #pragma unroll
        for (int b = 0; b < 4; ++b) acc[a][b] = (f32x4){0.f, 0.f, 0.f, 0.f};

    stage256(F, smem, 0, 0, rowA0, rowB0, tid);
    __syncthreads();

    for (int t = 0; t < 4; ++t) {
        const int cur = t & 1;
        if (t < 3) stage256(F, smem, cur ^ 1, (t + 1) * 64, rowA0, rowB0, tid);
        const char* Ab = smem + cur * 32768;
        const char* Bb = Ab + 16384;
        #pragma unroll
        for (int kk = 0; kk < 2; ++kk) {
            bf16x8 af[4], bfr[4];
            #pragma unroll
            for (int a = 0; a < 4; ++a) {
                int r = wr * 64 + a * 16 + lr;
                int pc = (kk * 4 + kg) ^ (r & 7);
                af[a] = *(const bf16x8*)(Ab + r * 128 + pc * 16);
            }
            #pragma unroll
            for (int b = 0; b < 4; ++b) {
                int r = wc * 64 + b * 16 + lr;
                int pc = (kk * 4 + kg) ^ (r & 7);
                bfr[b] = *(const bf16x8*)(Bb + r * 128 + pc * 16);
            }
            #pragma unroll
            for (int a = 0; a < 4; ++a)
                #pragma unroll
                for (int b = 0; b < 4; ++b)
                    acc[a][b] = __builtin_amdgcn_mfma_f32_16x16x32_bf16(af[a], bfr[b], acc[a][b], 0, 0, 0);
        }
        __syncthreads();
    }

    const int i0 = rowA0 + wr * 64;
    const int j0 = rowB0 + wc * 64;
    const float invT = 1.0f / 0.07f;
    const float slope = 1.0f / (float)NNEIGH;
    float rs[4][4];
    #pragma unroll
    for (int a = 0; a < 4; ++a)
        #pragma unroll
        for (int e = 0; e < 4; ++e) rs[a][e] = 0.f;

    #pragma unroll
    for (int a = 0; a < 4; ++a) {
        #pragma unroll
        for (int b = 0; b < 4; ++b) {
            const int col = j0 + b * 16 + lr;
            #pragma unroll
            for (int e = 0; e < 4; ++e) {
                const int row = i0 + a * 16 + kg * 4 + e;
                const int d = col - row;
                float wv = (d >= 0) ? fminf((float)d * slope, 1.0f)
                                    : ((d >= -NNEIGH) ? (float)(-d - 1) * slope : 1.0f);
                float v = __expf(acc[a][b][e] * invT) * wv;
                rs[a][e] += v;
                int pc = row + M_HALF;
                if (pc >= N_TOTAL) pc -= N_TOTAL;
                if (col == pc) num[row] = v;
            }
        }
    }
    #pragma unroll
    for (int a = 0; a < 4; ++a)
        #pragma unroll
        for (int e = 0; e < 4; ++e) {
            float s = rs[a][e];
            s += __shfl_xor(s, 1, 64);
            s += __shfl_xor(s, 2, 64);
            s += __shfl_xor(s, 4, 64);
            s += __shfl_xor(s, 8, 64);
            if (lr == 0) atomicAdd(&den[i0 + a * 16 + kg * 4 + e], s);
        }
}

__global__ __launch_bounds__(256) void fin_kernel(const float* __restrict__ num,
                                                  const float* __restrict__ den,
                                                  float* __restrict__ out) {
    __shared__ float sbuf[4];
    const int tid = threadIdx.x;
    float s = 0.f;
    for (int i = tid; i < N_TOTAL; i += 256) s += num[i] / den[i];
    s += __shfl_xor(s, 1, 64);
    s += __shfl_xor(s, 2, 64);
    s += __shfl_xor(s, 4, 64);
    s += __shfl_xor(s, 8, 64);
    s += __shfl_xor(s, 16, 64);
    s += __shfl_xor(s, 32, 64);
    if ((tid & 63) == 0) sbuf[tid >> 6] = s;
    __syncthreads();
    if (tid == 0) out[0] = (sbuf[0] + sbuf[1] + sbuf[2] + sbuf[3]) * (1.0f / (float)N_TOTAL);
}

extern "C" void kernel_launch(void* const* d_in, const int* in_sizes, int n_in,
                              void* d_out, int out_size, void* d_ws, size_t ws_size,
                              hipStream_t stream) {
    const float* emb = (const float*)d_in[0];
    // masks (d_in[1]) and labelvecs (d_in[2]) unused by the reference output
    uint16_t* F = (uint16_t*)d_ws;
    float* den = (float*)((char*)d_ws + (size_t)N_TOTAL * DIMS * sizeof(uint16_t));
    float* num = den + N_TOTAL;
    float* out = (float*)d_out;

    void* args[] = {(void*)&emb, (void*)&F, (void*)&den, (void*)&num, (void*)&out};
    hipError_t err = hipLaunchCooperativeKernel((const void*)fused_kernel,
                                                dim3(GRID), dim3(512), args, 0, stream);
    if (err != hipSuccess) {
        (void)hipGetLastError();  // clear sticky error, then verified 3-kernel path
        nt_kernel<<<dim3(256), dim3(256), 0, stream>>>(emb, F, den);
        sim_kernel<<<dim3(NTILES), dim3(256), 0, stream>>>(F, den, num);
        fin_kernel<<<dim3(1), dim3(256), 0, stream>>>(num, den, out);
    }
}

// Round 7
// 95.806 us; speedup vs baseline: 2.8844x; 2.8844x over previous
//
#include <hip/hip_runtime.h>
#include <stdint.h>

#define N_TOTAL 4096
#define DIMS 256
#define M_HALF 2048
#define NNEIGH 30
#define NTILES 1024   // (4096/128)^2

typedef __bf16 bf16_t;
typedef bf16_t bf16x8 __attribute__((ext_vector_type(8)));
typedef float f32x4 __attribute__((ext_vector_type(4)));

typedef __attribute__((address_space(3))) uint32_t lds_u32;
typedef const __attribute__((address_space(1))) uint32_t glb_u32;

__device__ inline uint16_t f2bf(float f) {
    union { float f; uint32_t u; } v; v.f = f;
    uint32_t u = v.u;
    uint32_t r = (u + 0x7fffu + ((u >> 16) & 1u)) >> 16;  // RNE
    return (uint16_t)r;
}

// Normalize + transpose: emb[16][256 d][256 l] f32 -> F[4096 r][256 d] bf16.
// Also zeroes den[] and the sim completion counter (dispatch boundary
// publishes these to all XCDs before sim runs).
__global__ __launch_bounds__(256) void nt_kernel(const float* __restrict__ emb,
                                                 uint16_t* __restrict__ F,
                                                 float* __restrict__ den,
                                                 int* __restrict__ counter) {
    __shared__ float tile[16][257];
    __shared__ float invn[16];
    const int bi = blockIdx.x >> 4;
    const int lc = blockIdx.x & 15;
    const int l0 = lc * 16;
    const int tid = threadIdx.x;
    if (tid < 16) den[blockIdx.x * 16 + tid] = 0.f;
    if (blockIdx.x == 0 && tid == 0) *counter = 0;
    const float* src = emb + (size_t)bi * DIMS * 256 + l0;
    #pragma unroll
    for (int p = 0; p < 16; ++p) {
        int idx = p * 256 + tid;
        int l = idx & 15;
        int d = idx >> 4;
        tile[l][d] = src[(size_t)d * 256 + l];
    }
    __syncthreads();
    {
        int l = tid >> 4;
        int c = tid & 15;
        float ss = 0.f;
        #pragma unroll
        for (int d = 0; d < 256; d += 16) {
            float v = tile[l][d + c];
            ss += v * v;
        }
        ss += __shfl_xor(ss, 1, 64);
        ss += __shfl_xor(ss, 2, 64);
        ss += __shfl_xor(ss, 4, 64);
        ss += __shfl_xor(ss, 8, 64);
        if (c == 0) invn[l] = 1.0f / fmaxf(sqrtf(ss), 1e-12f);
    }
    __syncthreads();
    #pragma unroll
    for (int p = 0; p < 16; ++p) {
        int r = bi * 256 + l0 + p;
        F[(size_t)r * DIMS + tid] = f2bf(tile[p][tid] * invn[p]);
    }
}

// Stage a 128x64 bf16 panel pair into LDS buffer `buf`. LDS dest linear
// (global_load_lds rule #21); XOR swizzle applied via the GLOBAL source chunk.
__device__ inline void stage256(const uint16_t* __restrict__ F, char* smem,
                                int buf, int k0, int rowA0, int rowB0, int tid) {
    const int wid = tid >> 6;
    #pragma unroll
    for (int i = 0; i < 4; ++i) {
        int p = i * 256 + tid;
        int row = p >> 3;
        int pc = p & 7;
        int c = pc ^ (row & 7);
        const uint16_t* ga = F + (size_t)(rowA0 + row) * DIMS + k0 + c * 8;
        char* la = smem + buf * 32768 + i * 4096 + wid * 1024;
        __builtin_amdgcn_global_load_lds((glb_u32*)ga, (lds_u32*)la, 16, 0, 0);
    }
    #pragma unroll
    for (int i = 0; i < 4; ++i) {
        int p = i * 256 + tid;
        int row = p >> 3;
        int pc = p & 7;
        int c = pc ^ (row & 7);
        const uint16_t* gb = F + (size_t)(rowB0 + row) * DIMS + k0 + c * 8;
        char* lb = smem + buf * 32768 + 16384 + i * 4096 + wid * 1024;
        __builtin_amdgcn_global_load_lds((glb_u32*)gb, (lds_u32*)lb, 16, 0, 0);
    }
}

// 128x128 tile of sims = F*F^T per block (4 waves, 2x2 quadrants), LDS-staged,
// double-buffered, fused exp/weight epilogue. Last block to finish performs
// the final mean reduction (completion-counter pattern; fences per R6 model).
__global__ __launch_bounds__(256) void sim_kernel(const uint16_t* __restrict__ F,
                                                  float* __restrict__ den,
                                                  float* __restrict__ num,
                                                  float* __restrict__ out,
                                                  int* __restrict__ counter) {
    __shared__ char smem[65536];
    const int tid = threadIdx.x;
    const int wid = tid >> 6;
    const int lane = tid & 63;
    const int lr = lane & 15;
    const int kg = lane >> 4;
    const int wr = wid >> 1, wc = wid & 1;

    const int bid = blockIdx.x;
    const int swz = (bid & 7) * 128 + (bid >> 3);  // XCD-aware, bijective (1024 = 8*128)
    const int bm = swz >> 5, bn = swz & 31;
    const int rowA0 = bm * 128, rowB0 = bn * 128;

    f32x4 acc[4][4];
    #pragma unroll
    for (int a = 0; a < 4; ++a)
        #pragma unroll
        for (int b = 0; b < 4; ++b) acc[a][b] = (f32x4){0.f, 0.f, 0.f, 0.f};

    stage256(F, smem, 0, 0, rowA0, rowB0, tid);
    __syncthreads();

    for (int t = 0; t < 4; ++t) {
        const int cur = t & 1;
        if (t < 3) stage256(F, smem, cur ^ 1, (t + 1) * 64, rowA0, rowB0, tid);
        const char* Ab = smem + cur * 32768;
        const char* Bb = Ab + 16384;
        #pragma unroll
        for (int kk = 0; kk < 2; ++kk) {
            bf16x8 af[4], bfr[4];
            #pragma unroll
            for (int a = 0; a < 4; ++a) {
                int r = wr * 64 + a * 16 + lr;
                int pc = (kk * 4 + kg) ^ (r & 7);
                af[a] = *(const bf16x8*)(Ab + r * 128 + pc * 16);
            }
            #pragma unroll
            for (int b = 0; b < 4; ++b) {
                int r = wc * 64 + b * 16 + lr;
                int pc = (kk * 4 + kg) ^ (r & 7);
                bfr[b] = *(const bf16x8*)(Bb + r * 128 + pc * 16);
            }
            #pragma unroll
            for (int a = 0; a < 4; ++a)
                #pragma unroll
                for (int b = 0; b < 4; ++b)
                    acc[a][b] = __builtin_amdgcn_mfma_f32_16x16x32_bf16(af[a], bfr[b], acc[a][b], 0, 0, 0);
        }
        __syncthreads();
    }

    const int i0 = rowA0 + wr * 64;
    const int j0 = rowB0 + wc * 64;
    const float K2 = 1.442695041f / 0.07f;           // exp(x/T) = exp2(x*K2)
    const float slope = 1.0f / (float)NNEIGH;
    const bool hasPartner = (((bn - bm) & 31) == 16); // only these tiles touch num
    float rs[4][4];
    #pragma unroll
    for (int a = 0; a < 4; ++a)
        #pragma unroll
        for (int e = 0; e < 4; ++e) rs[a][e] = 0.f;

    #pragma unroll
    for (int a = 0; a < 4; ++a) {
        #pragma unroll
        for (int b = 0; b < 4; ++b) {
            const int col = j0 + b * 16 + lr;
            #pragma unroll
            for (int e = 0; e < 4; ++e) {
                const int row = i0 + a * 16 + kg * 4 + e;
                const int d = col - row;
                // w: d==0 ->0; 0<d<30 -> d/30; d>=30 ->1; -30<=d<0 -> (-d-1)/30; d<-30 ->1
                // == min(((d>=0)? d : ~d) * slope, 1)   (and ~d == d^(d>>31) here)
                const int dm = d ^ (d >> 31);
                float wv = fminf((float)dm * slope, 1.0f);
                float v = exp2f(acc[a][b][e] * K2) * wv;
                rs[a][e] += v;
                if (hasPartner && ((d & (N_TOTAL - 1)) == M_HALF)) num[row] = v;
            }
        }
    }
    #pragma unroll
    for (int a = 0; a < 4; ++a)
        #pragma unroll
        for (int e = 0; e < 4; ++e) {
            float s = rs[a][e];
            s += __shfl_xor(s, 1, 64);
            s += __shfl_xor(s, 2, 64);
            s += __shfl_xor(s, 4, 64);
            s += __shfl_xor(s, 8, 64);
            if (lr == 0) atomicAdd(&den[i0 + a * 16 + kg * 4 + e], s);
        }

    // ---- last-block final reduction ----
    __shared__ int lastFlag;
    __threadfence();          // release: publish num stores (den is atomic already)
    __syncthreads();          // all threads of this block have fenced
    if (tid == 0) lastFlag = (atomicAdd(counter, 1) == NTILES - 1);
    __syncthreads();
    if (lastFlag) {
        __threadfence();      // acquire: invalidate stale lines before re-reading
        float* sb = (float*)smem;
        float s = 0.f;
        #pragma unroll
        for (int i = 0; i < N_TOTAL / 256; ++i) {
            int r = i * 256 + tid;
            s += num[r] / den[r];
        }
        s += __shfl_xor(s, 1, 64);
        s += __shfl_xor(s, 2, 64);
        s += __shfl_xor(s, 4, 64);
        s += __shfl_xor(s, 8, 64);
        s += __shfl_xor(s, 16, 64);
        s += __shfl_xor(s, 32, 64);
        if ((tid & 63) == 0) sb[tid >> 6] = s;
        __syncthreads();
        if (tid == 0) out[0] = (sb[0] + sb[1] + sb[2] + sb[3]) * (1.0f / (float)N_TOTAL);
    }
}

extern "C" void kernel_launch(void* const* d_in, const int* in_sizes, int n_in,
                              void* d_out, int out_size, void* d_ws, size_t ws_size,
                              hipStream_t stream) {
    const float* emb = (const float*)d_in[0];
    // masks (d_in[1]) and labelvecs (d_in[2]) unused by the reference output
    uint16_t* F = (uint16_t*)d_ws;
    float* den = (float*)((char*)d_ws + (size_t)N_TOTAL * DIMS * sizeof(uint16_t));
    float* num = den + N_TOTAL;
    int* counter = (int*)(num + N_TOTAL);
    float* out = (float*)d_out;

    nt_kernel<<<dim3(256), dim3(256), 0, stream>>>(emb, F, den, counter);
    sim_kernel<<<dim3(NTILES), dim3(256), 0, stream>>>(F, den, num, out, counter);
}

// Round 8
// 65.562 us; speedup vs baseline: 4.2151x; 1.4613x over previous
//
#include <hip/hip_runtime.h>
#include <stdint.h>

#define N_TOTAL 4096
#define DIMS 256
#define M_HALF 2048
#define NNEIGH 30
#define NTILES 1024   // (4096/128)^2

typedef __bf16 bf16_t;
typedef bf16_t bf16x8 __attribute__((ext_vector_type(8)));
typedef float f32x4 __attribute__((ext_vector_type(4)));

typedef __attribute__((address_space(3))) uint32_t lds_u32;
typedef const __attribute__((address_space(1))) uint32_t glb_u32;

__device__ inline uint16_t f2bf(float f) {
    union { float f; uint32_t u; } v; v.f = f;
    uint32_t u = v.u;
    uint32_t r = (u + 0x7fffu + ((u >> 16) & 1u)) >> 16;  // RNE
    return (uint16_t)r;
}

// Normalize + transpose: emb[16][256 d][256 l] f32 -> F[4096 r][256 d] bf16.
// Also zeroes den[] (dispatch boundary publishes to all XCDs before sim).
__global__ __launch_bounds__(256) void nt_kernel(const float* __restrict__ emb,
                                                 uint16_t* __restrict__ F,
                                                 float* __restrict__ den) {
    __shared__ float tile[16][257];
    __shared__ float invn[16];
    const int bi = blockIdx.x >> 4;
    const int lc = blockIdx.x & 15;
    const int l0 = lc * 16;
    const int tid = threadIdx.x;
    if (tid < 16) den[blockIdx.x * 16 + tid] = 0.f;
    const float* src = emb + (size_t)bi * DIMS * 256 + l0;
    #pragma unroll
    for (int p = 0; p < 16; ++p) {
        int idx = p * 256 + tid;
        int l = idx & 15;
        int d = idx >> 4;
        tile[l][d] = src[(size_t)d * 256 + l];
    }
    __syncthreads();
    {
        int l = tid >> 4;
        int c = tid & 15;
        float ss = 0.f;
        #pragma unroll
        for (int d = 0; d < 256; d += 16) {
            float v = tile[l][d + c];
            ss += v * v;
        }
        ss += __shfl_xor(ss, 1, 64);
        ss += __shfl_xor(ss, 2, 64);
        ss += __shfl_xor(ss, 4, 64);
        ss += __shfl_xor(ss, 8, 64);
        if (c == 0) invn[l] = 1.0f / fmaxf(sqrtf(ss), 1e-12f);
    }
    __syncthreads();
    #pragma unroll
    for (int p = 0; p < 16; ++p) {
        int r = bi * 256 + l0 + p;
        F[(size_t)r * DIMS + tid] = f2bf(tile[p][tid] * invn[p]);
    }
}

// Stage a 128x64 bf16 panel pair into LDS buffer `buf` (512 threads).
// LDS dest linear (global_load_lds rule #21); XOR swizzle via global source.
// Verified in R6's fused kernel (absmax 0.0).
__device__ inline void stage512(const uint16_t* __restrict__ F, char* smem,
                                int buf, int k0, int rowA0, int rowB0, int tid) {
    const int wid = tid >> 6;
    #pragma unroll
    for (int i = 0; i < 2; ++i) {
        int p = i * 512 + tid;          // 16B-chunk index within 16KB panel
        int row = p >> 3;
        int pc = p & 7;
        int c = pc ^ (row & 7);
        const uint16_t* ga = F + (size_t)(rowA0 + row) * DIMS + k0 + c * 8;
        char* la = smem + buf * 32768 + i * 8192 + wid * 1024;
        __builtin_amdgcn_global_load_lds((glb_u32*)ga, (lds_u32*)la, 16, 0, 0);
    }
    #pragma unroll
    for (int i = 0; i < 2; ++i) {
        int p = i * 512 + tid;
        int row = p >> 3;
        int pc = p & 7;
        int c = pc ^ (row & 7);
        const uint16_t* gb = F + (size_t)(rowB0 + row) * DIMS + k0 + c * 8;
        char* lb = smem + buf * 32768 + 16384 + i * 8192 + wid * 1024;
        __builtin_amdgcn_global_load_lds((glb_u32*)gb, (lds_u32*)lb, 16, 0, 0);
    }
}

// 128x128 tile of sims = F*F^T per block, 8 waves (2 row x 4 col, 64x32 each),
// 64KB double-buffered LDS -> 2 blocks/CU -> 16 waves/CU for latency hiding.
__global__ __launch_bounds__(512, 2) void sim_kernel(const uint16_t* __restrict__ F,
                                                     float* __restrict__ den,
                                                     float* __restrict__ num) {
    __shared__ char smem[65536];
    const int tid = threadIdx.x;
    const int wid = tid >> 6;
    const int lane = tid & 63;
    const int lr = lane & 15;
    const int kg = lane >> 4;
    const int wr = wid >> 2, wc = wid & 3;

    const int bid = blockIdx.x;
    const int swz = (bid & 7) * 128 + (bid >> 3);  // XCD-aware, bijective (1024 = 8*128)
    const int bm = swz >> 5, bn = swz & 31;
    const int rowA0 = bm * 128, rowB0 = bn * 128;

    f32x4 acc[4][2];
    #pragma unroll
    for (int a = 0; a < 4; ++a)
        #pragma unroll
        for (int bb = 0; bb < 2; ++bb) acc[a][bb] = (f32x4){0.f, 0.f, 0.f, 0.f};

    stage512(F, smem, 0, 0, rowA0, rowB0, tid);
    __syncthreads();

    for (int t = 0; t < 4; ++t) {
        const int cur = t & 1;
        if (t < 3) stage512(F, smem, cur ^ 1, (t + 1) * 64, rowA0, rowB0, tid);
        const char* Ab = smem + cur * 32768;
        const char* Bb = Ab + 16384;
        #pragma unroll
        for (int kk = 0; kk < 2; ++kk) {
            bf16x8 af[4], bfr[2];
            #pragma unroll
            for (int a = 0; a < 4; ++a) {
                int r = wr * 64 + a * 16 + lr;
                int pc = (kk * 4 + kg) ^ (r & 7);
                af[a] = *(const bf16x8*)(Ab + r * 128 + pc * 16);
            }
            #pragma unroll
            for (int bb = 0; bb < 2; ++bb) {
                int r = wc * 32 + bb * 16 + lr;
                int pc = (kk * 4 + kg) ^ (r & 7);
                bfr[bb] = *(const bf16x8*)(Bb + r * 128 + pc * 16);
            }
            #pragma unroll
            for (int a = 0; a < 4; ++a)
                #pragma unroll
                for (int bb = 0; bb < 2; ++bb)
                    acc[a][bb] = __builtin_amdgcn_mfma_f32_16x16x32_bf16(af[a], bfr[bb], acc[a][bb], 0, 0, 0);
        }
        __syncthreads();
    }

    const int i0 = rowA0 + wr * 64;
    const int j0 = rowB0 + wc * 32;
    const float K2 = 1.442695041f / 0.07f;            // exp(x/T) = exp2(x*K2)
    const float slope = 1.0f / (float)NNEIGH;
    const bool hasPartner = (((bn - bm) & 31) == 16); // only these tiles hold partner cols
    float rs[4][4];
    #pragma unroll
    for (int a = 0; a < 4; ++a)
        #pragma unroll
        for (int e = 0; e < 4; ++e) rs[a][e] = 0.f;

    #pragma unroll
    for (int a = 0; a < 4; ++a) {
        #pragma unroll
        for (int bb = 0; bb < 2; ++bb) {
            const int col = j0 + bb * 16 + lr;
            #pragma unroll
            for (int e = 0; e < 4; ++e) {
                const int row = i0 + a * 16 + kg * 4 + e;
                const int d = col - row;
                // w(d): 0 at d=0; min(|d|-ish slope,1): negative side uses ~d = d^(d>>31)
                const int dm = d ^ (d >> 31);
                float wv = fminf((float)dm * slope, 1.0f);
                float v = exp2f(acc[a][bb][e] * K2) * wv;
                rs[a][e] += v;
                if (hasPartner && ((d & (N_TOTAL - 1)) == M_HALF)) num[row] = v;
            }
        }
    }
    #pragma unroll
    for (int a = 0; a < 4; ++a)
        #pragma unroll
        for (int e = 0; e < 4; ++e) {
            float s = rs[a][e];
            s += __shfl_xor(s, 1, 64);
            s += __shfl_xor(s, 2, 64);
            s += __shfl_xor(s, 4, 64);
            s += __shfl_xor(s, 8, 64);
            if (lr == 0) atomicAdd(&den[i0 + a * 16 + kg * 4 + e], s);
        }
}

__global__ __launch_bounds__(256) void fin_kernel(const float* __restrict__ num,
                                                  const float* __restrict__ den,
                                                  float* __restrict__ out) {
    __shared__ float sbuf[4];
    const int tid = threadIdx.x;
    float s = 0.f;
    for (int i = tid; i < N_TOTAL; i += 256) s += num[i] / den[i];
    s += __shfl_xor(s, 1, 64);
    s += __shfl_xor(s, 2, 64);
    s += __shfl_xor(s, 4, 64);
    s += __shfl_xor(s, 8, 64);
    s += __shfl_xor(s, 16, 64);
    s += __shfl_xor(s, 32, 64);
    if ((tid & 63) == 0) sbuf[tid >> 6] = s;
    __syncthreads();
    if (tid == 0) out[0] = (sbuf[0] + sbuf[1] + sbuf[2] + sbuf[3]) * (1.0f / (float)N_TOTAL);
}

extern "C" void kernel_launch(void* const* d_in, const int* in_sizes, int n_in,
                              void* d_out, int out_size, void* d_ws, size_t ws_size,
                              hipStream_t stream) {
    const float* emb = (const float*)d_in[0];
    // masks (d_in[1]) and labelvecs (d_in[2]) unused by the reference output
    uint16_t* F = (uint16_t*)d_ws;
    float* den = (float*)((char*)d_ws + (size_t)N_TOTAL * DIMS * sizeof(uint16_t));
    float* num = den + N_TOTAL;
    float* out = (float*)d_out;

    nt_kernel<<<dim3(256), dim3(256), 0, stream>>>(emb, F, den);
    sim_kernel<<<dim3(NTILES), dim3(512), 0, stream>>>(F, den, num);
    fin_kernel<<<dim3(1), dim3(256), 0, stream>>>(num, den, out);
}

// Round 9
// 48.661 us; speedup vs baseline: 5.6790x; 1.3473x over previous
//
#include <hip/hip_runtime.h>
#include <stdint.h>

#define N_TOTAL 4096
#define DIMS 256
#define M_HALF 2048
#define NNEIGH 30
#define NTILES 1024   // (4096/128)^2
#define NSLICE 32     // one den partial per bn

typedef __bf16 bf16_t;
typedef bf16_t bf16x8 __attribute__((ext_vector_type(8)));
typedef float f32x4 __attribute__((ext_vector_type(4)));

typedef __attribute__((address_space(3))) uint32_t lds_u32;
typedef const __attribute__((address_space(1))) uint32_t glb_u32;

__device__ inline uint16_t f2bf(float f) {
    union { float f; uint32_t u; } v; v.f = f;
    uint32_t u = v.u;
    uint32_t r = (u + 0x7fffu + ((u >> 16) & 1u)) >> 16;  // RNE
    return (uint16_t)r;
}

// Normalize + transpose: emb[16][256 d][256 l] f32 -> F[4096 r][256 d] bf16.
__global__ __launch_bounds__(256) void nt_kernel(const float* __restrict__ emb,
                                                 uint16_t* __restrict__ F) {
    __shared__ float tile[16][257];
    __shared__ float invn[16];
    const int bi = blockIdx.x >> 4;
    const int lc = blockIdx.x & 15;
    const int l0 = lc * 16;
    const int tid = threadIdx.x;
    const float* src = emb + (size_t)bi * DIMS * 256 + l0;
    #pragma unroll
    for (int p = 0; p < 16; ++p) {
        int idx = p * 256 + tid;
        int l = idx & 15;
        int d = idx >> 4;
        tile[l][d] = src[(size_t)d * 256 + l];
    }
    __syncthreads();
    {
        int l = tid >> 4;
        int c = tid & 15;
        float ss = 0.f;
        #pragma unroll
        for (int d = 0; d < 256; d += 16) {
            float v = tile[l][d + c];
            ss += v * v;
        }
        ss += __shfl_xor(ss, 1, 64);
        ss += __shfl_xor(ss, 2, 64);
        ss += __shfl_xor(ss, 4, 64);
        ss += __shfl_xor(ss, 8, 64);
        if (c == 0) invn[l] = 1.0f / fmaxf(sqrtf(ss), 1e-12f);
    }
    __syncthreads();
    #pragma unroll
    for (int p = 0; p < 16; ++p) {
        int r = bi * 256 + l0 + p;
        F[(size_t)r * DIMS + tid] = f2bf(tile[p][tid] * invn[p]);
    }
}

// Stage a 128x64 bf16 panel pair into LDS buffer `buf` (256 threads).
// LDS dest linear (global_load_lds rule #21); XOR swizzle via global source.
__device__ inline void stage256(const uint16_t* __restrict__ F, char* smem,
                                int buf, int k0, int rowA0, int rowB0, int tid) {
    const int wid = tid >> 6;
    #pragma unroll
    for (int i = 0; i < 4; ++i) {
        int p = i * 256 + tid;
        int row = p >> 3;
        int pc = p & 7;
        int c = pc ^ (row & 7);
        const uint16_t* ga = F + (size_t)(rowA0 + row) * DIMS + k0 + c * 8;
        char* la = smem + buf * 32768 + i * 4096 + wid * 1024;
        __builtin_amdgcn_global_load_lds((glb_u32*)ga, (lds_u32*)la, 16, 0, 0);
    }
    #pragma unroll
    for (int i = 0; i < 4; ++i) {
        int p = i * 256 + tid;
        int row = p >> 3;
        int pc = p & 7;
        int c = pc ^ (row & 7);
        const uint16_t* gb = F + (size_t)(rowB0 + row) * DIMS + k0 + c * 8;
        char* lb = smem + buf * 32768 + 16384 + i * 4096 + wid * 1024;
        __builtin_amdgcn_global_load_lds((glb_u32*)gb, (lds_u32*)lb, 16, 0, 0);
    }
}

// 128x128 tile of sims = F*F^T per block (4 waves, 2x2 quadrants), LDS-staged,
// double-buffered, fused exp/weight epilogue. NO ATOMICS: per-tile row sums are
// combined across the two column-waves in LDS and plain-stored to
// den_part[row*32 + bn] (unique writer per element).
__global__ __launch_bounds__(256) void sim_kernel(const uint16_t* __restrict__ F,
                                                  float* __restrict__ den_part,
                                                  float* __restrict__ num) {
    __shared__ char smem[65536];
    const int tid = threadIdx.x;
    const int wid = tid >> 6;
    const int lane = tid & 63;
    const int lr = lane & 15;
    const int kg = lane >> 4;
    const int wr = wid >> 1, wc = wid & 1;

    const int bid = blockIdx.x;
    const int swz = (bid & 7) * 128 + (bid >> 3);  // XCD-aware, bijective (1024 = 8*128)
    const int bm = swz >> 5, bn = swz & 31;
    const int rowA0 = bm * 128, rowB0 = bn * 128;

    f32x4 acc[4][4];
    #pragma unroll
    for (int a = 0; a < 4; ++a)
        #pragma unroll
        for (int b = 0; b < 4; ++b) acc[a][b] = (f32x4){0.f, 0.f, 0.f, 0.f};

    stage256(F, smem, 0, 0, rowA0, rowB0, tid);
    __syncthreads();

    for (int t = 0; t < 4; ++t) {
        const int cur = t & 1;
        if (t < 3) stage256(F, smem, cur ^ 1, (t + 1) * 64, rowA0, rowB0, tid);
        const char* Ab = smem + cur * 32768;
        const char* Bb = Ab + 16384;
        #pragma unroll
        for (int kk = 0; kk < 2; ++kk) {
            bf16x8 af[4], bfr[4];
            #pragma unroll
            for (int a = 0; a < 4; ++a) {
                int r = wr * 64 + a * 16 + lr;
                int pc = (kk * 4 + kg) ^ (r & 7);
                af[a] = *(const bf16x8*)(Ab + r * 128 + pc * 16);
            }
            #pragma unroll
            for (int b = 0; b < 4; ++b) {
                int r = wc * 64 + b * 16 + lr;
                int pc = (kk * 4 + kg) ^ (r & 7);
                bfr[b] = *(const bf16x8*)(Bb + r * 128 + pc * 16);
            }
            #pragma unroll
            for (int a = 0; a < 4; ++a)
                #pragma unroll
                for (int b = 0; b < 4; ++b)
                    acc[a][b] = __builtin_amdgcn_mfma_f32_16x16x32_bf16(af[a], bfr[b], acc[a][b], 0, 0, 0);
        }
        __syncthreads();
    }

    const int i0 = rowA0 + wr * 64;
    const int j0 = rowB0 + wc * 64;
    const float K2 = 1.442695041f / 0.07f;            // exp(x/T) = exp2(x*K2)
    const float slope = 1.0f / (float)NNEIGH;
    const bool hasPartner = (((bn - bm) & 31) == 16); // only these tiles hold partner cols
    float srow[4][4];

    #pragma unroll
    for (int a = 0; a < 4; ++a) {
        #pragma unroll
        for (int e = 0; e < 4; ++e) srow[a][e] = 0.f;
    }
    #pragma unroll
    for (int a = 0; a < 4; ++a) {
        #pragma unroll
        for (int b = 0; b < 4; ++b) {
            const int col = j0 + b * 16 + lr;
            #pragma unroll
            for (int e = 0; e < 4; ++e) {
                const int row = i0 + a * 16 + kg * 4 + e;
                const int d = col - row;
                // w(d): 0 at d=0; right: min(d/30,1); left: min(~d/30,1); ~d == d^(d>>31)
                const int dm = d ^ (d >> 31);
                float wv = fminf((float)dm * slope, 1.0f);
                float v = exp2f(acc[a][b][e] * K2) * wv;
                srow[a][e] += v;
                if (hasPartner && ((d & (N_TOTAL - 1)) == M_HALF)) num[row] = v;
            }
        }
    }
    // reduce across the 16 lr lanes (cols of sub-tile); lr==0 lanes hold row sums
    #pragma unroll
    for (int a = 0; a < 4; ++a)
        #pragma unroll
        for (int e = 0; e < 4; ++e) {
            float s = srow[a][e];
            s += __shfl_xor(s, 1, 64);
            s += __shfl_xor(s, 2, 64);
            s += __shfl_xor(s, 4, 64);
            s += __shfl_xor(s, 8, 64);
            srow[a][e] = s;
        }
    // combine the two column-waves (wc=0,1) per row in LDS, then plain store
    float* cmb = (float*)smem;   // [128 rows][2 wc]; safe: all LDS reads done
    if (lr == 0) {
        #pragma unroll
        for (int a = 0; a < 4; ++a)
            #pragma unroll
            for (int e = 0; e < 4; ++e)
                cmb[(wr * 64 + a * 16 + kg * 4 + e) * 2 + wc] = srow[a][e];
    }
    __syncthreads();
    if (tid < 128)
        den_part[(size_t)(rowA0 + tid) * NSLICE + bn] = cmb[tid * 2] + cmb[tid * 2 + 1];
}

// Sum the 32 den partials per row, form num/den, reduce to the scalar mean.
__global__ __launch_bounds__(1024) void fin_kernel(const float* __restrict__ num,
                                                   const float* __restrict__ den_part,
                                                   float* __restrict__ out) {
    __shared__ float sb[16];
    const int tid = threadIdx.x;
    float s = 0.f;
    #pragma unroll
    for (int i = 0; i < N_TOTAL / 1024; ++i) {
        int r = i * 1024 + tid;
        const f32x4* dp = (const f32x4*)(den_part + (size_t)r * NSLICE);
        f32x4 acc4 = dp[0];
        #pragma unroll
        for (int k = 1; k < NSLICE / 4; ++k) acc4 += dp[k];
        float den = acc4[0] + acc4[1] + acc4[2] + acc4[3];
        s += num[r] / den;
    }
    s += __shfl_xor(s, 1, 64);
    s += __shfl_xor(s, 2, 64);
    s += __shfl_xor(s, 4, 64);
    s += __shfl_xor(s, 8, 64);
    s += __shfl_xor(s, 16, 64);
    s += __shfl_xor(s, 32, 64);
    if ((tid & 63) == 0) sb[tid >> 6] = s;
    __syncthreads();
    if (tid == 0) {
        float t = 0.f;
        #pragma unroll
        for (int w = 0; w < 16; ++w) t += sb[w];
        out[0] = t * (1.0f / (float)N_TOTAL);
    }
}

extern "C" void kernel_launch(void* const* d_in, const int* in_sizes, int n_in,
                              void* d_out, int out_size, void* d_ws, size_t ws_size,
                              hipStream_t stream) {
    const float* emb = (const float*)d_in[0];
    // masks (d_in[1]) and labelvecs (d_in[2]) unused by the reference output
    uint16_t* F = (uint16_t*)d_ws;                                   // 2 MB
    float* num = (float*)((char*)d_ws + (size_t)N_TOTAL * DIMS * 2); // 16 KB
    float* den_part = num + N_TOTAL;                                 // 512 KB
    float* out = (float*)d_out;

    nt_kernel<<<dim3(256), dim3(256), 0, stream>>>(emb, F);
    sim_kernel<<<dim3(NTILES), dim3(256), 0, stream>>>(F, den_part, num);
    fin_kernel<<<dim3(1), dim3(1024), 0, stream>>>(num, den_part, out);
}